// Round 17
// baseline (520.926 us; speedup 1.0000x reference)
//
#include <hip/hip_runtime.h>
#include <hip/hip_bf16.h>
#include <cstddef>

#define NF 13824
#define NM 512
#define NIC 27

typedef __attribute__((ext_vector_type(8))) short bf16x8;
typedef __attribute__((ext_vector_type(4))) float f32x4;

__device__ __forceinline__ float fexp2(float x){ return __builtin_amdgcn_exp2f(x); }

__device__ __forceinline__ void gload16(const float* g, float* l){
  __builtin_amdgcn_global_load_lds((const __attribute__((address_space(1))) void*)g,
                                   (__attribute__((address_space(3))) void*)l, 16, 0, 0);
}

// ---------------- merged weight transposes ----------------
__global__ void k_transpose6(const float* __restrict__ s0, float* __restrict__ d0,
                             const float* __restrict__ s1, float* __restrict__ d1,
                             const float* __restrict__ s2, float* __restrict__ d2,
                             const float* __restrict__ s3, float* __restrict__ d3,
                             const float* __restrict__ s4, float* __restrict__ d4,
                             const float* __restrict__ s5, float* __restrict__ d5){
  const float* W; float* WT; int Cout, Cin;
  switch (blockIdx.y){
    case 0: W=s0; WT=d0; Cout=512; Cin=128; break;
    case 1: W=s1; WT=d1; Cout=512; Cin=128; break;
    case 2: W=s2; WT=d2; Cout=128; Cin=256; break;
    case 3: W=s3; WT=d3; Cout=128; Cin=256; break;
    case 4: W=s4; WT=d4; Cout=512; Cin=128; break;
    default: W=s5; WT=d5; Cout=128; Cin=512; break;
  }
  int idx = blockIdx.x*256 + threadIdx.x;
  if (idx >= Cout*Cin) return;
  int co = idx / Cin, ci = idx % Cin;
  WT[(size_t)ci*Cout + co] = W[idx];
}

// ---------------- per-row (b,c) mean/var over N (+ fused affine when tf!=null) ----------------
__global__ void k_stats(const float* __restrict__ in, float2* __restrict__ st, int N,
                        float2* __restrict__ tf){
  int row = blockIdx.x;
  const float* p = in + (size_t)row*N;
  float s=0.f, q=0.f;
  int n4 = N/4;
  for (int i=threadIdx.x; i<n4; i+=256){
    float4 v = *(const float4*)(p + i*4);
    s += v.x+v.y+v.z+v.w;
    q += v.x*v.x+v.y*v.y+v.z*v.z+v.w*v.w;
  }
  __shared__ float rs[256], rq[256];
  rs[threadIdx.x]=s; rq[threadIdx.x]=q;
  __syncthreads();
  for (int o=128;o>0;o>>=1){
    if (threadIdx.x<o){ rs[threadIdx.x]+=rs[threadIdx.x+o]; rq[threadIdx.x]+=rq[threadIdx.x+o]; }
    __syncthreads();
  }
  if (threadIdx.x==0){
    float m = rs[0]/N;
    float v = rq[0]/N - m*m;
    if (v<0.f) v=0.f;
    st[row] = make_float2(m, v);
    if (tf){
      float a = rsqrtf(v + 1e-5f);
      tf[row] = make_float2(a, -m*a);
    }
  }
}

// ---------------- (m,v) stats (+ SE scale) -> affine (a,b) ----------------
__global__ void k_make_tf(const float2* __restrict__ st, const float* __restrict__ sbuf,
                          float2* __restrict__ tf, int rows){
  int i = blockIdx.x*256 + threadIdx.x;
  if (i>=rows) return;
  float s = sbuf ? sbuf[i] : 1.f;
  float2 mv = st[i];
  float a = s*rsqrtf(s*s*mv.y + 1e-5f);
  tf[i] = make_float2(a, -mv.x*a);
}

// ---------------- reduce per-block raw-sum partials -> affine (a,b); one wave per row ----------------
__global__ void k_red(const float2* __restrict__ part, int nparts, int rows,
                      float invN, float2* __restrict__ tf){
  int w = threadIdx.x>>6, l = threadIdx.x&63;
  int row = blockIdx.x*4 + w;
  if (row >= rows) return;
  const float2* p = part + (size_t)row*nparts;
  float s=0.f, q=0.f;
  for (int k=l; k<nparts; k+=64){ float2 v = p[k]; s += v.x; q += v.y; }
  s += __shfl_xor(s,1); s += __shfl_xor(s,2); s += __shfl_xor(s,4);
  s += __shfl_xor(s,8); s += __shfl_xor(s,16); s += __shfl_xor(s,32);
  q += __shfl_xor(q,1); q += __shfl_xor(q,2); q += __shfl_xor(q,4);
  q += __shfl_xor(q,8); q += __shfl_xor(q,16); q += __shfl_xor(q,32);
  if (l==0){
    float m = s*invN;
    float v = q*invN - m*m;
    if (v<0.f) v=0.f;
    float a = rsqrtf(v + 1e-5f);
    tf[row] = make_float2(a, -m*a);
  }
}

// ---------------- elementwise relu(a*v+b) per (b,c) row ----------------
__global__ void k_act(const float* __restrict__ in, const float2* __restrict__ tf,
                      float* __restrict__ outp){
  int i = blockIdx.x*256 + threadIdx.x;   // float4 index
  int n4 = i*4;
  int bc = n4 / NF;
  float2 t = tf[bc];
  float4 v = *(const float4*)(in + n4);
  v.x = fmaxf(t.x*v.x + t.y, 0.f);
  v.y = fmaxf(t.x*v.y + t.y, 0.f);
  v.z = fmaxf(t.x*v.z + t.y, 0.f);
  v.w = fmaxf(t.x*v.w + t.y, 0.f);
  *(float4*)(outp + n4) = v;
}

// ---------------- fold per-(b,ci) affine into weights + bias ----------------
__global__ void k_fold(const float* __restrict__ wt, const float2* __restrict__ tf,
                       float* __restrict__ wf, float* __restrict__ bias){
  int co = blockIdx.x;            // 128
  int b  = blockIdx.y;            // 2
  float partb = 0.f;
  for (int ci=threadIdx.x; ci<512; ci+=256){
    float w = wt[ci*128 + co];
    float2 t = tf[b*512 + ci];
    wf[((size_t)b*512 + ci)*128 + co] = w * t.x;
    partb += w * t.y;
  }
  __shared__ float red[256];
  red[threadIdx.x] = partb; __syncthreads();
  for (int o=128;o>0;o>>=1){ if (threadIdx.x<o) red[threadIdx.x]+=red[threadIdx.x+o]; __syncthreads(); }
  if (threadIdx.x==0) bias[b*128 + co] = red[0];
}

// ---------------- depthwise 3x3x3 conv on 24^3 via LDS-staged channel ----------------
__global__ __launch_bounds__(256) void k_dw3t(const float* __restrict__ in, const float* __restrict__ w,
                      const float2* __restrict__ tf, float* __restrict__ out,
                      int C, int relu, float2* __restrict__ stout){
  int bc = blockIdx.x;
  int c = bc % C;
  __shared__ float lds[4 + 26*728];          // 75728 B
  __shared__ float rs2[256], rq2[256];
  float a = 1.f, bb = 0.f;
  if (tf){ float2 t = tf[bc]; a=t.x; bb=t.y; }

  {
    float4* l4 = (float4*)lds;
    float4 z = make_float4(0.f,0.f,0.f,0.f);
    for (int i=threadIdx.x; i<(4+26*728)/4; i+=256) l4[i] = z;
  }
  __syncthreads();

  const float* pin = in + (size_t)bc*NF;
  for (int i=threadIdx.x; i<NF/4; i+=256){
    int n = i*4;
    int d = n/576, r2 = n%576;
    int h = r2/24, wq = r2%24;
    float4 v = *(const float4*)(pin + n);
    float v0 = a*v.x+bb, v1 = a*v.y+bb, v2 = a*v.z+bb, v3 = a*v.w+bb;
    if (relu){ v0=fmaxf(v0,0.f); v1=fmaxf(v1,0.f); v2=fmaxf(v2,0.f); v3=fmaxf(v3,0.f); }
    *(float4*)(lds + 4 + (d+1)*728 + (h+1)*28 + wq) = make_float4(v0,v1,v2,v3);
  }

  const float* wc = w + c*27;
  float wr[27];
  #pragma unroll
  for (int k=0;k<27;k++) wr[k] = wc[k];
  __syncthreads();

  float ss=0.f, sq=0.f;
  for (int r = threadIdx.x; r < 576; r += 256){
    int d = r/24, h = r%24;
    float acc[24];
    #pragma unroll
    for (int i=0;i<24;i++) acc[i] = 0.f;
    #pragma unroll
    for (int kd=0;kd<3;kd++){
      #pragma unroll
      for (int kh=0;kh<3;kh++){
        const float* row = lds + 4 + (d+kd)*728 + (h+kh)*28;
        float rr[24];
        #pragma unroll
        for (int q=0;q<6;q++){
          float4 v4 = *(const float4*)(row + 4*q);
          rr[4*q]=v4.x; rr[4*q+1]=v4.y; rr[4*q+2]=v4.z; rr[4*q+3]=v4.w;
        }
        float rl = row[-1];
        float rrgt = row[24];
        float w0 = wr[kd*9+kh*3+0], w1 = wr[kd*9+kh*3+1], w2 = wr[kd*9+kh*3+2];
        acc[0] += w0*rl + w1*rr[0] + w2*rr[1];
        #pragma unroll
        for (int i=1;i<23;i++) acc[i] += w0*rr[i-1] + w1*rr[i] + w2*rr[i+1];
        acc[23] += w0*rr[22] + w1*rr[23] + w2*rrgt;
      }
    }
    if (stout){
      #pragma unroll
      for (int i=0;i<24;i++){ ss += acc[i]; sq += acc[i]*acc[i]; }
    }
    float* op = out + (size_t)bc*NF + r*24;
    #pragma unroll
    for (int q=0;q<6;q++)
      *(float4*)(op + 4*q) = make_float4(acc[4*q],acc[4*q+1],acc[4*q+2],acc[4*q+3]);
  }
  if (stout){
    rs2[threadIdx.x]=ss; rq2[threadIdx.x]=sq;
    __syncthreads();
    for (int o=128;o>0;o>>=1){
      if (threadIdx.x<o){ rs2[threadIdx.x]+=rs2[threadIdx.x+o]; rq2[threadIdx.x]+=rq2[threadIdx.x+o]; }
      __syncthreads();
    }
    if (threadIdx.x==0){
      float m = rs2[0]/NF;
      float v = rq2[0]/NF - m*m;
      stout[bc] = make_float2(m, v>0.f? v:0.f);
    }
  }
}

// ---------------- big pointwise SGEMM: 128co x 64n tile, async global->LDS dbuf ----------------
__global__ __launch_bounds__(256) void k_pw2(const float* __restrict__ in, const float* __restrict__ Wt,
                    const float* __restrict__ bias,
                    int Cin, int Cout, int N, int wstride,
                    const float* __restrict__ res,
                    float* __restrict__ out0,
                    __hip_bfloat16* __restrict__ qnm, __hip_bfloat16* __restrict__ vdm,
                    int mode, float2* __restrict__ part, int nparts){
  int b = blockIdx.z;
  int n0 = blockIdx.x*64, co0 = blockIdx.y*128;
  int t = threadIdx.x;
  int tx = t & 15, tyy = t >> 4;
  int wv = t >> 6, ln = t & 63;
  __shared__ float wl[2][32*128];
  __shared__ float il[2][32*64];
  float acc[8][4] = {};
  const float* inb = in + (size_t)b*Cin*N;
  const float* wb  = Wt + (size_t)b*wstride;

  int wrow = (ln>>5), wcol = (ln&31)*4;
  int irow = (ln>>4), icol = (ln&15)*4;

  auto STAGE = [&](int c0, int buf){
    #pragma unroll
    for (int k=0;k<4;k++){
      int row = wv*8 + 2*k + wrow;
      gload16(wb + (size_t)(c0+row)*Cout + co0 + wcol, &wl[buf][row*128 + wcol]);
    }
    #pragma unroll
    for (int k=0;k<2;k++){
      int row = wv*8 + 4*k + irow;
      gload16(inb + (size_t)(c0+row)*N + n0 + icol, &il[buf][row*64 + icol]);
    }
  };

  STAGE(0, 0);
  __syncthreads();

  int nc = Cin >> 5;
  int cur = 0;
  for (int c=0; c<nc; c++){
    if (c+1 < nc) STAGE((c+1)*32, cur^1);
    #pragma unroll
    for (int ci=0;ci<32;ci++){
      const float* wr2 = &wl[cur][ci*128 + tyy*8];
      float4 w0 = *(const float4*)(wr2);
      float4 w1 = *(const float4*)(wr2+4);
      float4 b4 = *(const float4*)&il[cur][ci*64 + tx*4];
      acc[0][0]+=w0.x*b4.x; acc[0][1]+=w0.x*b4.y; acc[0][2]+=w0.x*b4.z; acc[0][3]+=w0.x*b4.w;
      acc[1][0]+=w0.y*b4.x; acc[1][1]+=w0.y*b4.y; acc[1][2]+=w0.y*b4.z; acc[1][3]+=w0.y*b4.w;
      acc[2][0]+=w0.z*b4.x; acc[2][1]+=w0.z*b4.y; acc[2][2]+=w0.z*b4.z; acc[2][3]+=w0.z*b4.w;
      acc[3][0]+=w0.w*b4.x; acc[3][1]+=w0.w*b4.y; acc[3][2]+=w0.w*b4.z; acc[3][3]+=w0.w*b4.w;
      acc[4][0]+=w1.x*b4.x; acc[4][1]+=w1.x*b4.y; acc[4][2]+=w1.x*b4.z; acc[4][3]+=w1.x*b4.w;
      acc[5][0]+=w1.y*b4.x; acc[5][1]+=w1.y*b4.y; acc[5][2]+=w1.y*b4.z; acc[5][3]+=w1.y*b4.w;
      acc[6][0]+=w1.z*b4.x; acc[6][1]+=w1.z*b4.y; acc[6][2]+=w1.z*b4.z; acc[6][3]+=w1.z*b4.w;
      acc[7][0]+=w1.w*b4.x; acc[7][1]+=w1.w*b4.y; acc[7][2]+=w1.w*b4.z; acc[7][3]+=w1.w*b4.w;
    }
    __syncthreads();
    cur ^= 1;
  }

  if (mode==0){
    #pragma unroll
    for (int i=0;i<8;i++){
      int co = co0 + tyy*8 + i;
      float bco = bias ? bias[b*Cout + co] : 0.f;
      float* op = out0 + ((size_t)b*Cout + co)*N;
      float sv=0.f, qv=0.f;
      #pragma unroll
      for (int j=0;j<4;j++){
        int n = n0 + tx*4 + j;
        float v = acc[i][j] + bco;
        if (res) v += res[((size_t)b*Cout + co)*N + n];
        op[n] = v;
        sv += v; qv += v*v;
      }
      if (part){
        sv += __shfl_xor(sv,1); sv += __shfl_xor(sv,2); sv += __shfl_xor(sv,4); sv += __shfl_xor(sv,8);
        qv += __shfl_xor(qv,1); qv += __shfl_xor(qv,2); qv += __shfl_xor(qv,4); qv += __shfl_xor(qv,8);
        if (tx==0)
          part[(size_t)(b*Cout + co)*nparts + blockIdx.x] = make_float2(sv, qv);
      }
    }
  } else {
    bool isq = (co0 < 256);
    #pragma unroll
    for (int i=0;i<8;i++){
      int co = co0 + tyy*8 + i;
      int head = co & 3, dd = (co & 255) >> 2;
      int bhid = b*4 + head;
      #pragma unroll
      for (int j=0;j<4;j++){
        int n = n0 + tx*4 + j;
        __hip_bfloat16 v = __float2bfloat16(acc[i][j]);
        if (isq) qnm[((size_t)bhid*N + n)*64 + dd] = v;
        else     vdm[((size_t)(bhid*64 + dd))*N + n] = v;
      }
    }
  }
}

// ---------------- small-grid pointwise SGEMM: 64co x 64n tile, async dbuf ----------------
__global__ __launch_bounds__(256) void k_pw2s(const float* __restrict__ in, const float* __restrict__ Wt,
                    const float* __restrict__ bias,
                    int Cin, int Cout, int N, int wstride,
                    const float* __restrict__ res,
                    float* __restrict__ out0,
                    int mode, float2* __restrict__ part, int nparts){
  int b = blockIdx.z;
  int n0 = blockIdx.x*64, co0 = blockIdx.y*64;
  int t = threadIdx.x;
  int tx = t & 15, ty = t >> 4;
  int wv = t >> 6, ln = t & 63;
  __shared__ float wl[2][32*64];
  __shared__ float il[2][32*64];
  float acc[4][4] = {};
  const float* inb = in + (size_t)b*Cin*N;
  const float* wb  = Wt + (size_t)b*wstride;

  int row4 = (ln>>4), col4 = (ln&15)*4;

  auto STAGE = [&](int c0, int buf){
    #pragma unroll
    for (int k=0;k<2;k++){
      int row = wv*8 + 4*k + row4;
      gload16(wb  + (size_t)(c0+row)*Cout + co0 + col4, &wl[buf][row*64 + col4]);
      gload16(inb + (size_t)(c0+row)*N    + n0  + col4, &il[buf][row*64 + col4]);
    }
  };

  STAGE(0, 0);
  __syncthreads();

  int nc = Cin >> 5;
  int cur = 0;
  for (int c=0; c<nc; c++){
    if (c+1 < nc) STAGE((c+1)*32, cur^1);
    #pragma unroll
    for (int ci=0;ci<32;ci++){
      float4 a4 = *(const float4*)&wl[cur][ci*64 + ty*4];
      float4 b4 = *(const float4*)&il[cur][ci*64 + tx*4];
      acc[0][0]+=a4.x*b4.x; acc[0][1]+=a4.x*b4.y; acc[0][2]+=a4.x*b4.z; acc[0][3]+=a4.x*b4.w;
      acc[1][0]+=a4.y*b4.x; acc[1][1]+=a4.y*b4.y; acc[1][2]+=a4.y*b4.z; acc[1][3]+=a4.y*b4.w;
      acc[2][0]+=a4.z*b4.x; acc[2][1]+=a4.z*b4.y; acc[2][2]+=a4.z*b4.z; acc[2][3]+=a4.z*b4.w;
      acc[3][0]+=a4.w*b4.x; acc[3][1]+=a4.w*b4.y; acc[3][2]+=a4.w*b4.z; acc[3][3]+=a4.w*b4.w;
    }
    __syncthreads();
    cur ^= 1;
  }

  #pragma unroll
  for (int i=0;i<4;i++){
    int co = co0 + ty*4 + i;
    float bco = bias ? bias[b*Cout + co] : 0.f;
    float* op = out0 + ((size_t)b*Cout + co)*N;
    float sv=0.f, qv=0.f;
    #pragma unroll
    for (int j=0;j<4;j++){
      int n = n0 + tx*4 + j;
      float v = acc[i][j] + bco;
      if (res) v += res[((size_t)b*Cout + co)*N + n];
      op[n] = v;
      sv += v; qv += v*v;
    }
    if (part){
      sv += __shfl_xor(sv,1); sv += __shfl_xor(sv,2); sv += __shfl_xor(sv,4); sv += __shfl_xor(sv,8);
      qv += __shfl_xor(qv,1); qv += __shfl_xor(qv,2); qv += __shfl_xor(qv,4); qv += __shfl_xor(qv,8);
      if (tx==0)
        part[(size_t)(b*Cout + co)*nparts + blockIdx.x] = make_float2(sv, qv);
    }
  }
  (void)mode;
}

// ---------------- small pointwise conv (NM-sized) ----------------
__global__ __launch_bounds__(256) void k_pw(const float* __restrict__ in, const float* __restrict__ WT,
                    const float2* __restrict__ tf, int relu,
                    int Cin, int Cout, int N,
                    const float* __restrict__ res,
                    float* __restrict__ out0,
                    __hip_bfloat16* __restrict__ qnm, __hip_bfloat16* __restrict__ vdm,
                    int mode){
  int b = blockIdx.z;
  int n0 = blockIdx.x*64, co0 = blockIdx.y*64;
  int tx = threadIdx.x & 15, ty = threadIdx.x >> 4;
  int cc = threadIdx.x & 63, g = threadIdx.x >> 6;
  __shared__ float wl[32][68];
  __shared__ float il[32][68];
  float acc[4][4] = {};
  const float* inb = in + (size_t)b*Cin*N;

  float rw[8], rv[8], ta[8], tb[8];
  #pragma unroll
  for (int rr=0;rr<8;rr++){ ta[rr]=1.f; tb[rr]=0.f; }
  #pragma unroll
  for (int rr=0;rr<8;rr++){
    int ci = g + 4*rr;
    rw[rr] = WT[(size_t)ci*Cout + co0 + cc];
    rv[rr] = inb[(size_t)ci*N + n0 + cc];
    if (tf){ float2 t = tf[b*Cin + ci]; ta[rr]=t.x; tb[rr]=t.y; }
  }

  for (int c0=0;c0<Cin;c0+=32){
    __syncthreads();
    #pragma unroll
    for (int rr=0;rr<8;rr++){
      int ci = g + 4*rr;
      wl[ci][cc] = rw[rr];
      float v = ta[rr]*rv[rr] + tb[rr];
      if (relu) v = fmaxf(v, 0.f);
      il[ci][cc] = v;
    }
    __syncthreads();
    if (c0+32 < Cin){
      int c0n = c0+32;
      #pragma unroll
      for (int rr=0;rr<8;rr++){
        int ci = g + 4*rr;
        rw[rr] = WT[(size_t)(c0n+ci)*Cout + co0 + cc];
        rv[rr] = inb[(size_t)(c0n+ci)*N + n0 + cc];
        if (tf){ float2 t = tf[b*Cin + c0n + ci]; ta[rr]=t.x; tb[rr]=t.y; }
      }
    }
    #pragma unroll
    for (int ci=0;ci<32;ci++){
      float4 a4 = *(const float4*)&wl[ci][ty*4];
      float4 b4 = *(const float4*)&il[ci][tx*4];
      acc[0][0]+=a4.x*b4.x; acc[0][1]+=a4.x*b4.y; acc[0][2]+=a4.x*b4.z; acc[0][3]+=a4.x*b4.w;
      acc[1][0]+=a4.y*b4.x; acc[1][1]+=a4.y*b4.y; acc[1][2]+=a4.y*b4.z; acc[1][3]+=a4.y*b4.w;
      acc[2][0]+=a4.z*b4.x; acc[2][1]+=a4.z*b4.y; acc[2][2]+=a4.z*b4.z; acc[2][3]+=a4.z*b4.w;
      acc[3][0]+=a4.w*b4.x; acc[3][1]+=a4.w*b4.y; acc[3][2]+=a4.w*b4.z; acc[3][3]+=a4.w*b4.w;
    }
  }
  if (mode==0){
    #pragma unroll
    for (int i=0;i<4;i++){
      int co = co0 + ty*4 + i;
      float* op = out0 + ((size_t)b*Cout + co)*N;
      #pragma unroll
      for (int j=0;j<4;j++){
        int n = n0 + tx*4 + j;
        float v = acc[i][j];
        if (res) v += res[((size_t)b*Cout + co)*N + n];
        op[n] = v;
      }
    }
  } else {
    int ccbase = (co0 & 255) + ty*4;
    int dd = ccbase >> 2;
    bool isq = (co0 < 256);
    #pragma unroll
    for (int i=0;i<4;i++){
      int bhid = b*4 + i;
      #pragma unroll
      for (int j=0;j<4;j++){
        int n = n0 + tx*4 + j;
        __hip_bfloat16 v = __float2bfloat16(acc[i][j]);
        if (isq) qnm[((size_t)bhid*N + n)*64 + dd] = v;
        else     vdm[((size_t)(bhid*64 + dd))*N + n] = v;
      }
    }
  }
}

// ---------------- merged attention: interleaved fattn (odd bid) / mattn (even bid) ----------------
// software-pipelined: exp(t) consumes QK results computed one phase earlier
__global__ __launch_bounds__(256) void k_attn(const __hip_bfloat16* __restrict__ qf,
    const __hip_bfloat16* __restrict__ qm, const __hip_bfloat16* __restrict__ vm,
    const __hip_bfloat16* __restrict__ vf,
    float* __restrict__ fo, float* __restrict__ num, float* __restrict__ cs){
  __shared__ __hip_bfloat16 pl[4][2][16][40];
  __shared__ float rsl[4][32];
  int bid = blockIdx.x;
  int sub = bid >> 1;
  int w = threadIdx.x>>6, l = threadIdx.x&63;
  int lr = l&15, lg = l>>4;

  if (bid & 1){
    // ---- feat-direction ----
    int bh = sub/108, b = bh>>2, h = bh&3;
    int i0 = (sub%108)*128 + w*32;
    bf16x8 aq[2][2];
    #pragma unroll
    for (int g=0; g<2; g++){
      const __hip_bfloat16* qb = qf + ((size_t)bh*NF + i0 + g*16 + lr)*64 + lg*8;
      aq[g][0] = *(const bf16x8*)(qb);
      aq[g][1] = *(const bf16x8*)(qb + 32);
    }
    f32x4 facc[2][4];
    #pragma unroll
    for (int g=0; g<2; g++)
      #pragma unroll
      for (int t=0;t<4;t++){ facc[g][t][0]=0.f; facc[g][t][1]=0.f; facc[g][t][2]=0.f; facc[g][t][3]=0.f; }
    float rs[2][4] = {};
    const __hip_bfloat16* kbase = qm + ((size_t)bh*NM + lr)*64 + lg*8;
    const __hip_bfloat16* vbase = vm + ((size_t)bh*64 + lr)*NM + lg*8;

    auto QKC = [&](bf16x8 K0, bf16x8 K1, bf16x8 K2, bf16x8 K3, f32x4 (&s)[2][2]){
      __builtin_amdgcn_s_setprio(1);
      #pragma unroll
      for (int g=0; g<2; g++){
        f32x4 s0 = {0.f,0.f,0.f,0.f}, s1 = {0.f,0.f,0.f,0.f};
        s0 = __builtin_amdgcn_mfma_f32_16x16x32_bf16(aq[g][0], K0, s0, 0,0,0);
        s0 = __builtin_amdgcn_mfma_f32_16x16x32_bf16(aq[g][1], K1, s0, 0,0,0);
        s1 = __builtin_amdgcn_mfma_f32_16x16x32_bf16(aq[g][0], K2, s1, 0,0,0);
        s1 = __builtin_amdgcn_mfma_f32_16x16x32_bf16(aq[g][1], K3, s1, 0,0,0);
        s[g][0] = s0; s[g][1] = s1;
      }
      __builtin_amdgcn_s_setprio(0);
    };
    auto EPV = [&](f32x4 (&s)[2][2], bf16x8 V0, bf16x8 V1, bf16x8 V2, bf16x8 V3){
      #pragma unroll
      for (int g=0; g<2; g++){
        #pragma unroll
        for (int r=0;r<4;r++){
          float p0 = fexp2(s[g][0][r]*0.18033688f);
          float p1 = fexp2(s[g][1][r]*0.18033688f);
          pl[w][g][4*lg+r][lr]    = __float2bfloat16(p0);
          pl[w][g][4*lg+r][16+lr] = __float2bfloat16(p1);
          rs[g][r] += p0 + p1;
        }
      }
      __builtin_amdgcn_s_setprio(1);
      #pragma unroll
      for (int g=0; g<2; g++){
        bf16x8 bp = *(const bf16x8*)&pl[w][g][lr][lg*8];
        facc[g][0] = __builtin_amdgcn_mfma_f32_16x16x32_bf16(V0, bp, facc[g][0], 0,0,0);
        facc[g][1] = __builtin_amdgcn_mfma_f32_16x16x32_bf16(V1, bp, facc[g][1], 0,0,0);
        facc[g][2] = __builtin_amdgcn_mfma_f32_16x16x32_bf16(V2, bp, facc[g][2], 0,0,0);
        facc[g][3] = __builtin_amdgcn_mfma_f32_16x16x32_bf16(V3, bp, facc[g][3], 0,0,0);
      }
      __builtin_amdgcn_s_setprio(0);
    };

    bf16x8 kA0,kA1,kA2,kA3,vA0,vA1,vA2,vA3;
    bf16x8 kB0,kB1,kB2,kB3,vB0,vB1,vB2,vB3;
    f32x4 sA[2][2], sB[2][2];
    #define FLOAD(KP,VP,J0) \
      KP##0 = *(const bf16x8*)(kbase + (size_t)(J0)*64); \
      KP##1 = *(const bf16x8*)(kbase + (size_t)(J0)*64 + 32); \
      KP##2 = *(const bf16x8*)(kbase + (size_t)(J0)*64 + 1024); \
      KP##3 = *(const bf16x8*)(kbase + (size_t)(J0)*64 + 1056); \
      VP##0 = *(const bf16x8*)(vbase + (J0)); \
      VP##1 = *(const bf16x8*)(vbase + 16*NM + (J0)); \
      VP##2 = *(const bf16x8*)(vbase + 32*NM + (J0)); \
      VP##3 = *(const bf16x8*)(vbase + 48*NM + (J0));

    FLOAD(kA,vA,0)
    QKC(kA0,kA1,kA2,kA3, sA);
    for (int jt=0; jt<16; jt+=2){
      FLOAD(kB,vB,(jt+1)*32)
      EPV(sA, vA0,vA1,vA2,vA3);
      QKC(kB0,kB1,kB2,kB3, sB);
      if (jt+2 < 16){ FLOAD(kA,vA,(jt+2)*32) }
      EPV(sB, vB0,vB1,vB2,vB3);
      if (jt+2 < 16){ QKC(kA0,kA1,kA2,kA3, sA); }
    }
    #undef FLOAD

    #pragma unroll
    for (int g=0; g<2; g++)
      #pragma unroll
      for (int r=0;r<4;r++){
        float v = rs[g][r];
        v += __shfl_xor(v,1); v += __shfl_xor(v,2); v += __shfl_xor(v,4); v += __shfl_xor(v,8);
        if (lr==0) rsl[w][g*16 + 4*lg+r] = v;
      }
    __syncthreads();
    #pragma unroll
    for (int g=0; g<2; g++){
      float inv = 1.f / rsl[w][g*16 + lr];
      #pragma unroll
      for (int dt=0; dt<4; dt++){
        #pragma unroll
        for (int r=0;r<4;r++){
          int d = dt*16 + 4*lg + r;
          fo[((size_t)(b*256 + d*4 + h))*NF + i0 + g*16 + lr] = facc[g][dt][r]*inv;
        }
      }
    }
  } else {
    // ---- map-direction: 2 j-groups per wave, register-loaded F/V, pipelined ----
    int ic = sub%27, jb = (sub/27)&3, bh = sub/108;
    int jt0 = jb*128 + w*16;
    int jt1 = jt0 + 64;
    bf16x8 am[2][2];
    {
      const __hip_bfloat16* ab0 = qm + ((size_t)bh*NM + jt0 + lr)*64 + lg*8;
      const __hip_bfloat16* ab1 = qm + ((size_t)bh*NM + jt1 + lr)*64 + lg*8;
      am[0][0] = *(const bf16x8*)(ab0);
      am[0][1] = *(const bf16x8*)(ab0 + 32);
      am[1][0] = *(const bf16x8*)(ab1);
      am[1][1] = *(const bf16x8*)(ab1 + 32);
    }
    f32x4 macc[2][4];
    #pragma unroll
    for (int jg=0;jg<2;jg++)
      #pragma unroll
      for (int t=0;t<4;t++){ macc[jg][t][0]=0.f; macc[jg][t][1]=0.f; macc[jg][t][2]=0.f; macc[jg][t][3]=0.f; }
    float csr[2][4] = {};
    const __hip_bfloat16* fbase  = qf + ((size_t)bh*NF + lr)*64 + lg*8;
    const __hip_bfloat16* vfbase = vf + ((size_t)bh*64 + lr)*NF + lg*8;

    auto QKC = [&](bf16x8 F0, bf16x8 F1, bf16x8 F2, bf16x8 F3, f32x4 (&s)[2][2]){
      __builtin_amdgcn_s_setprio(1);
      #pragma unroll
      for (int jg=0;jg<2;jg++){
        f32x4 s0 = {0.f,0.f,0.f,0.f}, s1 = {0.f,0.f,0.f,0.f};
        s0 = __builtin_amdgcn_mfma_f32_16x16x32_bf16(am[jg][0], F0, s0, 0,0,0);
        s0 = __builtin_amdgcn_mfma_f32_16x16x32_bf16(am[jg][1], F1, s0, 0,0,0);
        s1 = __builtin_amdgcn_mfma_f32_16x16x32_bf16(am[jg][0], F2, s1, 0,0,0);
        s1 = __builtin_amdgcn_mfma_f32_16x16x32_bf16(am[jg][1], F3, s1, 0,0,0);
        s[jg][0] = s0; s[jg][1] = s1;
      }
      __builtin_amdgcn_s_setprio(0);
    };
    auto EPV = [&](f32x4 (&s)[2][2], bf16x8 V0, bf16x8 V1, bf16x8 V2, bf16x8 V3){
      #pragma unroll
      for (int jg=0;jg<2;jg++){
        #pragma unroll
        for (int r=0;r<4;r++){
          float p0 = fexp2(s[jg][0][r]*0.18033688f);
          float p1 = fexp2(s[jg][1][r]*0.18033688f);
          pl[w][jg][4*lg+r][lr]    = __float2bfloat16(p0);
          pl[w][jg][4*lg+r][16+lr] = __float2bfloat16(p1);
          csr[jg][r] += p0 + p1;
        }
      }
      __builtin_amdgcn_s_setprio(1);
      #pragma unroll
      for (int jg=0;jg<2;jg++){
        bf16x8 bp = *(const bf16x8*)&pl[w][jg][lr][lg*8];
        macc[jg][0] = __builtin_amdgcn_mfma_f32_16x16x32_bf16(V0, bp, macc[jg][0], 0,0,0);
        macc[jg][1] = __builtin_amdgcn_mfma_f32_16x16x32_bf16(V1, bp, macc[jg][1], 0,0,0);
        macc[jg][2] = __builtin_amdgcn_mfma_f32_16x16x32_bf16(V2, bp, macc[jg][2], 0,0,0);
        macc[jg][3] = __builtin_amdgcn_mfma_f32_16x16x32_bf16(V3, bp, macc[jg][3], 0,0,0);
      }
      __builtin_amdgcn_s_setprio(0);
    };

    bf16x8 fA0,fA1,fA2,fA3,vA0,vA1,vA2,vA3;
    bf16x8 fB0,fB1,fB2,fB3,vB0,vB1,vB2,vB3;
    f32x4 sA[2][2], sB[2][2];
    #define MLOAD(FP,VP,I0) \
      FP##0 = *(const bf16x8*)(fbase + (size_t)(I0)*64); \
      FP##1 = *(const bf16x8*)(fbase + (size_t)(I0)*64 + 32); \
      FP##2 = *(const bf16x8*)(fbase + (size_t)(I0)*64 + 1024); \
      FP##3 = *(const bf16x8*)(fbase + (size_t)(I0)*64 + 1056); \
      VP##0 = *(const bf16x8*)(vfbase + (size_t)(I0)); \
      VP##1 = *(const bf16x8*)(vfbase + (size_t)16*NF + (I0)); \
      VP##2 = *(const bf16x8*)(vfbase + (size_t)32*NF + (I0)); \
      VP##3 = *(const bf16x8*)(vfbase + (size_t)48*NF + (I0));

    int ibase = ic*512;
    MLOAD(fA,vA, ibase)
    QKC(fA0,fA1,fA2,fA3, sA);
    for (int is=0; is<16; is+=2){
      MLOAD(fB,vB, ibase + (is+1)*32)
      EPV(sA, vA0,vA1,vA2,vA3);
      QKC(fB0,fB1,fB2,fB3, sB);
      if (is+2<16){ MLOAD(fA,vA, ibase + (is+2)*32) }
      EPV(sB, vB0,vB1,vB2,vB3);
      if (is+2<16){ QKC(fA0,fA1,fA2,fA3, sA); }
    }
    #undef MLOAD

    size_t nb = ((size_t)(ic*8 + bh)*64)*512;
    #pragma unroll
    for (int jg=0;jg<2;jg++){
      int jt = jg ? jt1 : jt0;
      #pragma unroll
      for (int dt=0;dt<4;dt++){
        #pragma unroll
        for (int r=0;r<4;r++){
          num[nb + (size_t)(dt*16 + 4*lg + r)*512 + jt + lr] = macc[jg][dt][r];
        }
      }
    }
    #pragma unroll
    for (int jg=0;jg<2;jg++){
      int jt = jg ? jt1 : jt0;
      #pragma unroll
      for (int r=0;r<4;r++){
        float v = csr[jg][r];
        v += __shfl_xor(v,1); v += __shfl_xor(v,2); v += __shfl_xor(v,4); v += __shfl_xor(v,8);
        if (lr==0) cs[(size_t)(ic*8 + bh)*512 + jt + 4*lg + r] = v;
      }
    }
  }
}

// ---------------- combine map-dir partials -> ma merged-channel layout (coalesced) ----------------
__global__ void k_comb(const float* __restrict__ num, const float* __restrict__ cs,
                       float* __restrict__ ma){
  int idx = blockIdx.x*256 + threadIdx.x;
  if (idx >= 8*512*64) return;
  int bh = idx>>15; int rem = idx&32767; int d = rem>>9; int j = rem&511;
  float s=0.f, c=0.f;
  for (int ic=0;ic<NIC;ic++){
    s += num[((size_t)(ic*8+bh)*64 + d)*512 + j];
    c += cs[(size_t)(ic*8+bh)*512 + j];
  }
  int b = bh>>2, h = bh&3;
  ma[((size_t)(b*256 + d*4 + h))*NM + j] = s/c;
}

// ---------------- squeeze-excite MLP (tiny) ----------------
__global__ void k_se(const float2* __restrict__ st, const float* __restrict__ w1, const float* __restrict__ b1,
                     const float* __restrict__ w2, const float* __restrict__ b2, float* __restrict__ sout){
  int b = blockIdx.x; int t = threadIdx.x;
  __shared__ float mean[512]; __shared__ float s1[128];
  mean[t]     = st[b*512 + t].x;
  mean[t+256] = st[b*512 + t + 256].x;
  __syncthreads();
  if (t<128){
    float a = b1[t];
    for (int c=0;c<512;c++) a += w1[t*512+c]*mean[c];
    s1[t] = fmaxf(a, 0.f);
  }
  __syncthreads();
  for (int o=t;o<512;o+=256){
    float a = b2[o];
    for (int c=0;c<128;c++) a += w2[o*128+c]*s1[c];
    sout[b*512+o] = 1.f/(1.f+__expf(-a));
  }
}

extern "C" void kernel_launch(void* const* d_in, const int* in_sizes, int n_in,
                              void* d_out, int out_size, void* d_ws, size_t ws_size,
                              hipStream_t stream){
  const float* x     = (const float*)d_in[0];
  const float* smap  = (const float*)d_in[1];
  const float* wfdw  = (const float*)d_in[2];
  const float* wfpw  = (const float*)d_in[3];
  const float* wmqv  = (const float*)d_in[4];
  const float* wodw  = (const float*)d_in[5];
  const float* wopw  = (const float*)d_in[6];
  const float* wmout = (const float*)d_in[7];
  const float* wexp  = (const float*)d_in[8];
  const float* wdw   = (const float*)d_in[9];
  const float* wse1  = (const float*)d_in[10];
  const float* bse1  = (const float*)d_in[11];
  const float* wse2  = (const float*)d_in[12];
  const float* bse2  = (const float*)d_in[13];
  const float* wpw   = (const float*)d_in[14];

  float* out  = (float*)d_out;                        // [2][128][NF]
  float* mout = out + (size_t)2*128*NF;               // [2][128][NM]

  float* W = (float*)d_ws;
  size_t o = 0;
  __hip_bfloat16* qf = (__hip_bfloat16*)(W + o); o += (size_t)8*NF*32;   // bf16 [8][NF][64]
  __hip_bfloat16* vf = (__hip_bfloat16*)(W + o); o += (size_t)8*NF*32;   // bf16 [8][64][NF]
  float* fdw  = W + o; o += (size_t)2*128*NF;          // reused as 'act' for MBConv expand
  float* num  = W + o; o += (size_t)NIC*8*64*512;
  __hip_bfloat16* qm = (__hip_bfloat16*)(W + o); o += 8*NM*32;           // bf16 [8][512][64]
  __hip_bfloat16* vm = (__hip_bfloat16*)(W + o); o += 8*NM*32;           // bf16 [8][64][512]
  float* csb  = W + o; o += (size_t)NIC*8*512;
  float* ma   = W + o; o += (size_t)2*256*NM;
  float* h2   = (float*)d_ws;
  float* fo   = W + o; o += (size_t)2*256*NF;
  float* fdw2 = W + o; o += (size_t)2*256*NF;
  float* h1 = fo;
  float* wTf  = W + o; o += 512*128;
  float* wTm  = W + o; o += 512*128;
  float* wTo  = W + o; o += 128*256;
  float* wTmo = W + o; o += 128*256;
  float* wTe  = W + o; o += 512*128;
  float* wTp  = W + o; o += 128*512;
  float* wfP  = W + o; o += (size_t)2*512*128;         // folded final weights
  float* biasP= W + o; o += 2*128;                     // folded final bias
  float2* partO = (float2*)(W+o); o += (size_t)2*256*216;
  float2* partH1= (float2*)(W+o); o += (size_t)2*1024*216;
  float2* tfO = (float2*)(W+o); o += 512;
  float2* tfH1= (float2*)(W+o); o += 2048;
  float2* stA = (float2*)(W+o); o += 512;
  float2* tfA = (float2*)(W+o); o += 512;
  float2* stM = (float2*)(W+o); o += 512;
  float2* tfM = (float2*)(W+o); o += 512;
  float2* stH2= (float2*)(W+o); o += 2048;
  float2* tfH = (float2*)(W+o); o += 2048;
  float* sbuf = W + o; o += 1024;
  (void)ws_size; (void)in_sizes; (void)n_in; (void)out_size;

  // merged weight transposes
  k_transpose6<<<dim3(256,6),256,0,stream>>>(wfpw,wTf, wmqv,wTm, wopw,wTo, wmout,wTmo, wexp,wTe, wpw,wTp);

  // feat path
  k_stats<<<256,256,0,stream>>>(x, stA, NF, tfA);
  k_dw3t<<<256,256,0,stream>>>(x, wfdw, tfA, fdw, 128, 0, nullptr);
  k_pw2<<<dim3(216,4,2),256,0,stream>>>(fdw, wTf, nullptr, 128,512,NF,0, nullptr, nullptr, qf, vf, 1, nullptr,0);

  // map path
  k_stats<<<256,256,0,stream>>>(smap, stM, NM, tfM);
  k_pw<<<dim3(8,8,2),256,0,stream>>>(smap, wTm, tfM,0, 128,512,NM, nullptr, nullptr, qm, vm, 1);

  // attention, both directions merged + interleaved (MFMA)
  k_attn<<<dim3(1728),256,0,stream>>>(qf, qm, vm, vf, fo, num, csb);
  k_comb<<<1024,256,0,stream>>>(num, csb, ma);

  // output convs + residuals (out stats via per-block partials -> partO)
  k_dw3t<<<512,256,0,stream>>>(fo, wodw, nullptr, fdw2, 256, 0, nullptr);
  k_pw2s<<<dim3(216,2,2),256,0,stream>>>(fdw2, wTo, nullptr, 256,128,NF,0, x, out, 0, partO,216);
  k_pw<<<dim3(8,2,2),256,0,stream>>>(ma, wTmo, nullptr,0, 256,128,NM, smap, mout, nullptr,nullptr, 0);

  // MBConv
  k_red<<<64,256,0,stream>>>(partO, 216, 256, 1.f/NF, tfO);
  k_act<<<3456,256,0,stream>>>(out, tfO, fdw);          // act = relu(inorm(out)), reuses fdw
  k_pw2<<<dim3(216,4,2),256,0,stream>>>(fdw, wTe, nullptr, 128,512,NF,0, nullptr, h1, nullptr,nullptr, 0, partH1,216);

  k_red<<<256,256,0,stream>>>(partH1, 216, 1024, 1.f/NF, tfH1);
  k_dw3t<<<1024,256,0,stream>>>(h1, wdw, tfH1, h2, 512, 1, stH2);

  k_se<<<2,256,0,stream>>>(stH2, wse1,bse1,wse2,bse2, sbuf);
  k_make_tf<<<4,256,0,stream>>>(stH2, sbuf, tfH, 1024);
  k_fold<<<dim3(128,2),256,0,stream>>>(wTp, tfH, wfP, biasP);
  k_pw2s<<<dim3(216,2,2),256,0,stream>>>(h2, wfP, biasP, 512,128,NF,512*128, out, out, 0, nullptr,0);
}

// Round 18
// 518.502 us; speedup vs baseline: 1.0047x; 1.0047x over previous
//
#include <hip/hip_runtime.h>
#include <hip/hip_bf16.h>
#include <cstddef>

#define NF 13824
#define NM 512
#define NIC 27

typedef __attribute__((ext_vector_type(8))) short bf16x8;
typedef __attribute__((ext_vector_type(4))) float f32x4;

__device__ __forceinline__ float fexp2(float x){ return __builtin_amdgcn_exp2f(x); }

__device__ __forceinline__ void gload16(const float* g, float* l){
  __builtin_amdgcn_global_load_lds((const __attribute__((address_space(1))) void*)g,
                                   (__attribute__((address_space(3))) void*)l, 16, 0, 0);
}

// ---------------- merged weight transposes ----------------
__global__ void k_transpose6(const float* __restrict__ s0, float* __restrict__ d0,
                             const float* __restrict__ s1, float* __restrict__ d1,
                             const float* __restrict__ s2, float* __restrict__ d2,
                             const float* __restrict__ s3, float* __restrict__ d3,
                             const float* __restrict__ s4, float* __restrict__ d4,
                             const float* __restrict__ s5, float* __restrict__ d5){
  const float* W; float* WT; int Cout, Cin;
  switch (blockIdx.y){
    case 0: W=s0; WT=d0; Cout=512; Cin=128; break;
    case 1: W=s1; WT=d1; Cout=512; Cin=128; break;
    case 2: W=s2; WT=d2; Cout=128; Cin=256; break;
    case 3: W=s3; WT=d3; Cout=128; Cin=256; break;
    case 4: W=s4; WT=d4; Cout=512; Cin=128; break;
    default: W=s5; WT=d5; Cout=128; Cin=512; break;
  }
  int idx = blockIdx.x*256 + threadIdx.x;
  if (idx >= Cout*Cin) return;
  int co = idx / Cin, ci = idx % Cin;
  WT[(size_t)ci*Cout + co] = W[idx];
}

// ---------------- per-row (b,c) mean/var over N (+ fused affine when tf!=null) ----------------
__global__ void k_stats(const float* __restrict__ in, float2* __restrict__ st, int N,
                        float2* __restrict__ tf){
  int row = blockIdx.x;
  const float* p = in + (size_t)row*N;
  float s=0.f, q=0.f;
  int n4 = N/4;
  for (int i=threadIdx.x; i<n4; i+=256){
    float4 v = *(const float4*)(p + i*4);
    s += v.x+v.y+v.z+v.w;
    q += v.x*v.x+v.y*v.y+v.z*v.z+v.w*v.w;
  }
  __shared__ float rs[256], rq[256];
  rs[threadIdx.x]=s; rq[threadIdx.x]=q;
  __syncthreads();
  for (int o=128;o>0;o>>=1){
    if (threadIdx.x<o){ rs[threadIdx.x]+=rs[threadIdx.x+o]; rq[threadIdx.x]+=rq[threadIdx.x+o]; }
    __syncthreads();
  }
  if (threadIdx.x==0){
    float m = rs[0]/N;
    float v = rq[0]/N - m*m;
    if (v<0.f) v=0.f;
    st[row] = make_float2(m, v);
    if (tf){
      float a = rsqrtf(v + 1e-5f);
      tf[row] = make_float2(a, -m*a);
    }
  }
}

// ---------------- (m,v) stats (+ SE scale) -> affine (a,b) ----------------
__global__ void k_make_tf(const float2* __restrict__ st, const float* __restrict__ sbuf,
                          float2* __restrict__ tf, int rows){
  int i = blockIdx.x*256 + threadIdx.x;
  if (i>=rows) return;
  float s = sbuf ? sbuf[i] : 1.f;
  float2 mv = st[i];
  float a = s*rsqrtf(s*s*mv.y + 1e-5f);
  tf[i] = make_float2(a, -mv.x*a);
}

// ---------------- reduce per-block raw-sum partials -> affine (a,b); one wave per row ----------------
__global__ void k_red(const float2* __restrict__ part, int nparts, int rows,
                      float invN, float2* __restrict__ tf){
  int w = threadIdx.x>>6, l = threadIdx.x&63;
  int row = blockIdx.x*4 + w;
  if (row >= rows) return;
  const float2* p = part + (size_t)row*nparts;
  float s=0.f, q=0.f;
  for (int k=l; k<nparts; k+=64){ float2 v = p[k]; s += v.x; q += v.y; }
  s += __shfl_xor(s,1); s += __shfl_xor(s,2); s += __shfl_xor(s,4);
  s += __shfl_xor(s,8); s += __shfl_xor(s,16); s += __shfl_xor(s,32);
  q += __shfl_xor(q,1); q += __shfl_xor(q,2); q += __shfl_xor(q,4);
  q += __shfl_xor(q,8); q += __shfl_xor(q,16); q += __shfl_xor(q,32);
  if (l==0){
    float m = s*invN;
    float v = q*invN - m*m;
    if (v<0.f) v=0.f;
    float a = rsqrtf(v + 1e-5f);
    tf[row] = make_float2(a, -m*a);
  }
}

// ---------------- elementwise relu(a*v+b) per (b,c) row ----------------
__global__ void k_act(const float* __restrict__ in, const float2* __restrict__ tf,
                      float* __restrict__ outp){
  int i = blockIdx.x*256 + threadIdx.x;   // float4 index
  int n4 = i*4;
  int bc = n4 / NF;
  float2 t = tf[bc];
  float4 v = *(const float4*)(in + n4);
  v.x = fmaxf(t.x*v.x + t.y, 0.f);
  v.y = fmaxf(t.x*v.y + t.y, 0.f);
  v.z = fmaxf(t.x*v.z + t.y, 0.f);
  v.w = fmaxf(t.x*v.w + t.y, 0.f);
  *(float4*)(outp + n4) = v;
}

// ---------------- fold per-(b,ci) affine into weights + bias ----------------
__global__ void k_fold(const float* __restrict__ wt, const float2* __restrict__ tf,
                       float* __restrict__ wf, float* __restrict__ bias){
  int co = blockIdx.x;            // 128
  int b  = blockIdx.y;            // 2
  float partb = 0.f;
  for (int ci=threadIdx.x; ci<512; ci+=256){
    float w = wt[ci*128 + co];
    float2 t = tf[b*512 + ci];
    wf[((size_t)b*512 + ci)*128 + co] = w * t.x;
    partb += w * t.y;
  }
  __shared__ float red[256];
  red[threadIdx.x] = partb; __syncthreads();
  for (int o=128;o>0;o>>=1){ if (threadIdx.x<o) red[threadIdx.x]+=red[threadIdx.x+o]; __syncthreads(); }
  if (threadIdx.x==0) bias[b*128 + co] = red[0];
}

// ---------------- depthwise 3x3x3 conv on 24^3 via LDS-staged channel ----------------
__global__ __launch_bounds__(256) void k_dw3t(const float* __restrict__ in, const float* __restrict__ w,
                      const float2* __restrict__ tf, float* __restrict__ out,
                      int C, int relu, float2* __restrict__ stout){
  int bc = blockIdx.x;
  int c = bc % C;
  __shared__ float lds[4 + 26*728];          // 75728 B
  __shared__ float rs2[256], rq2[256];
  float a = 1.f, bb = 0.f;
  if (tf){ float2 t = tf[bc]; a=t.x; bb=t.y; }

  {
    float4* l4 = (float4*)lds;
    float4 z = make_float4(0.f,0.f,0.f,0.f);
    for (int i=threadIdx.x; i<(4+26*728)/4; i+=256) l4[i] = z;
  }
  __syncthreads();

  const float* pin = in + (size_t)bc*NF;
  for (int i=threadIdx.x; i<NF/4; i+=256){
    int n = i*4;
    int d = n/576, r2 = n%576;
    int h = r2/24, wq = r2%24;
    float4 v = *(const float4*)(pin + n);
    float v0 = a*v.x+bb, v1 = a*v.y+bb, v2 = a*v.z+bb, v3 = a*v.w+bb;
    if (relu){ v0=fmaxf(v0,0.f); v1=fmaxf(v1,0.f); v2=fmaxf(v2,0.f); v3=fmaxf(v3,0.f); }
    *(float4*)(lds + 4 + (d+1)*728 + (h+1)*28 + wq) = make_float4(v0,v1,v2,v3);
  }

  const float* wc = w + c*27;
  float wr[27];
  #pragma unroll
  for (int k=0;k<27;k++) wr[k] = wc[k];
  __syncthreads();

  float ss=0.f, sq=0.f;
  for (int r = threadIdx.x; r < 576; r += 256){
    int d = r/24, h = r%24;
    float acc[24];
    #pragma unroll
    for (int i=0;i<24;i++) acc[i] = 0.f;
    #pragma unroll
    for (int kd=0;kd<3;kd++){
      #pragma unroll
      for (int kh=0;kh<3;kh++){
        const float* row = lds + 4 + (d+kd)*728 + (h+kh)*28;
        float rr[24];
        #pragma unroll
        for (int q=0;q<6;q++){
          float4 v4 = *(const float4*)(row + 4*q);
          rr[4*q]=v4.x; rr[4*q+1]=v4.y; rr[4*q+2]=v4.z; rr[4*q+3]=v4.w;
        }
        float rl = row[-1];
        float rrgt = row[24];
        float w0 = wr[kd*9+kh*3+0], w1 = wr[kd*9+kh*3+1], w2 = wr[kd*9+kh*3+2];
        acc[0] += w0*rl + w1*rr[0] + w2*rr[1];
        #pragma unroll
        for (int i=1;i<23;i++) acc[i] += w0*rr[i-1] + w1*rr[i] + w2*rr[i+1];
        acc[23] += w0*rr[22] + w1*rr[23] + w2*rrgt;
      }
    }
    if (stout){
      #pragma unroll
      for (int i=0;i<24;i++){ ss += acc[i]; sq += acc[i]*acc[i]; }
    }
    float* op = out + (size_t)bc*NF + r*24;
    #pragma unroll
    for (int q=0;q<6;q++)
      *(float4*)(op + 4*q) = make_float4(acc[4*q],acc[4*q+1],acc[4*q+2],acc[4*q+3]);
  }
  if (stout){
    rs2[threadIdx.x]=ss; rq2[threadIdx.x]=sq;
    __syncthreads();
    for (int o=128;o>0;o>>=1){
      if (threadIdx.x<o){ rs2[threadIdx.x]+=rs2[threadIdx.x+o]; rq2[threadIdx.x]+=rq2[threadIdx.x+o]; }
      __syncthreads();
    }
    if (threadIdx.x==0){
      float m = rs2[0]/NF;
      float v = rq2[0]/NF - m*m;
      stout[bc] = make_float2(m, v>0.f? v:0.f);
    }
  }
}

// ---------------- big pointwise SGEMM: 128co x 64n tile, async global->LDS dbuf ----------------
__global__ __launch_bounds__(256) void k_pw2(const float* __restrict__ in, const float* __restrict__ Wt,
                    const float* __restrict__ bias,
                    int Cin, int Cout, int N, int wstride,
                    const float* __restrict__ res,
                    float* __restrict__ out0,
                    __hip_bfloat16* __restrict__ qnm, __hip_bfloat16* __restrict__ vdm,
                    int mode, float2* __restrict__ part, int nparts){
  int b = blockIdx.z;
  int n0 = blockIdx.x*64, co0 = blockIdx.y*128;
  int t = threadIdx.x;
  int tx = t & 15, tyy = t >> 4;
  int wv = t >> 6, ln = t & 63;
  __shared__ float wl[2][32*128];
  __shared__ float il[2][32*64];
  float acc[8][4] = {};
  const float* inb = in + (size_t)b*Cin*N;
  const float* wb  = Wt + (size_t)b*wstride;

  int wrow = (ln>>5), wcol = (ln&31)*4;
  int irow = (ln>>4), icol = (ln&15)*4;

  auto STAGE = [&](int c0, int buf){
    #pragma unroll
    for (int k=0;k<4;k++){
      int row = wv*8 + 2*k + wrow;
      gload16(wb + (size_t)(c0+row)*Cout + co0 + wcol, &wl[buf][row*128 + wcol]);
    }
    #pragma unroll
    for (int k=0;k<2;k++){
      int row = wv*8 + 4*k + irow;
      gload16(inb + (size_t)(c0+row)*N + n0 + icol, &il[buf][row*64 + icol]);
    }
  };

  STAGE(0, 0);
  __syncthreads();

  int nc = Cin >> 5;
  int cur = 0;
  for (int c=0; c<nc; c++){
    if (c+1 < nc) STAGE((c+1)*32, cur^1);
    #pragma unroll
    for (int ci=0;ci<32;ci++){
      const float* wr2 = &wl[cur][ci*128 + tyy*8];
      float4 w0 = *(const float4*)(wr2);
      float4 w1 = *(const float4*)(wr2+4);
      float4 b4 = *(const float4*)&il[cur][ci*64 + tx*4];
      acc[0][0]+=w0.x*b4.x; acc[0][1]+=w0.x*b4.y; acc[0][2]+=w0.x*b4.z; acc[0][3]+=w0.x*b4.w;
      acc[1][0]+=w0.y*b4.x; acc[1][1]+=w0.y*b4.y; acc[1][2]+=w0.y*b4.z; acc[1][3]+=w0.y*b4.w;
      acc[2][0]+=w0.z*b4.x; acc[2][1]+=w0.z*b4.y; acc[2][2]+=w0.z*b4.z; acc[2][3]+=w0.z*b4.w;
      acc[3][0]+=w0.w*b4.x; acc[3][1]+=w0.w*b4.y; acc[3][2]+=w0.w*b4.z; acc[3][3]+=w0.w*b4.w;
      acc[4][0]+=w1.x*b4.x; acc[4][1]+=w1.x*b4.y; acc[4][2]+=w1.x*b4.z; acc[4][3]+=w1.x*b4.w;
      acc[5][0]+=w1.y*b4.x; acc[5][1]+=w1.y*b4.y; acc[5][2]+=w1.y*b4.z; acc[5][3]+=w1.y*b4.w;
      acc[6][0]+=w1.z*b4.x; acc[6][1]+=w1.z*b4.y; acc[6][2]+=w1.z*b4.z; acc[6][3]+=w1.z*b4.w;
      acc[7][0]+=w1.w*b4.x; acc[7][1]+=w1.w*b4.y; acc[7][2]+=w1.w*b4.z; acc[7][3]+=w1.w*b4.w;
    }
    __syncthreads();
    cur ^= 1;
  }

  if (mode==0){
    #pragma unroll
    for (int i=0;i<8;i++){
      int co = co0 + tyy*8 + i;
      float bco = bias ? bias[b*Cout + co] : 0.f;
      float* op = out0 + ((size_t)b*Cout + co)*N;
      float sv=0.f, qv=0.f;
      #pragma unroll
      for (int j=0;j<4;j++){
        int n = n0 + tx*4 + j;
        float v = acc[i][j] + bco;
        if (res) v += res[((size_t)b*Cout + co)*N + n];
        op[n] = v;
        sv += v; qv += v*v;
      }
      if (part){
        sv += __shfl_xor(sv,1); sv += __shfl_xor(sv,2); sv += __shfl_xor(sv,4); sv += __shfl_xor(sv,8);
        qv += __shfl_xor(qv,1); qv += __shfl_xor(qv,2); qv += __shfl_xor(qv,4); qv += __shfl_xor(qv,8);
        if (tx==0)
          part[(size_t)(b*Cout + co)*nparts + blockIdx.x] = make_float2(sv, qv);
      }
    }
  } else {
    bool isq = (co0 < 256);
    #pragma unroll
    for (int i=0;i<8;i++){
      int co = co0 + tyy*8 + i;
      int head = co & 3, dd = (co & 255) >> 2;
      int bhid = b*4 + head;
      #pragma unroll
      for (int j=0;j<4;j++){
        int n = n0 + tx*4 + j;
        __hip_bfloat16 v = __float2bfloat16(acc[i][j]);
        if (isq) qnm[((size_t)bhid*N + n)*64 + dd] = v;
        else     vdm[((size_t)(bhid*64 + dd))*N + n] = v;
      }
    }
  }
}

// ---------------- small-grid pointwise SGEMM: 64co x 64n tile, async dbuf ----------------
__global__ __launch_bounds__(256) void k_pw2s(const float* __restrict__ in, const float* __restrict__ Wt,
                    const float* __restrict__ bias,
                    int Cin, int Cout, int N, int wstride,
                    const float* __restrict__ res,
                    float* __restrict__ out0,
                    int mode, float2* __restrict__ part, int nparts){
  int b = blockIdx.z;
  int n0 = blockIdx.x*64, co0 = blockIdx.y*64;
  int t = threadIdx.x;
  int tx = t & 15, ty = t >> 4;
  int wv = t >> 6, ln = t & 63;
  __shared__ float wl[2][32*64];
  __shared__ float il[2][32*64];
  float acc[4][4] = {};
  const float* inb = in + (size_t)b*Cin*N;
  const float* wb  = Wt + (size_t)b*wstride;

  int row4 = (ln>>4), col4 = (ln&15)*4;

  auto STAGE = [&](int c0, int buf){
    #pragma unroll
    for (int k=0;k<2;k++){
      int row = wv*8 + 4*k + row4;
      gload16(wb  + (size_t)(c0+row)*Cout + co0 + col4, &wl[buf][row*64 + col4]);
      gload16(inb + (size_t)(c0+row)*N    + n0  + col4, &il[buf][row*64 + col4]);
    }
  };

  STAGE(0, 0);
  __syncthreads();

  int nc = Cin >> 5;
  int cur = 0;
  for (int c=0; c<nc; c++){
    if (c+1 < nc) STAGE((c+1)*32, cur^1);
    #pragma unroll
    for (int ci=0;ci<32;ci++){
      float4 a4 = *(const float4*)&wl[cur][ci*64 + ty*4];
      float4 b4 = *(const float4*)&il[cur][ci*64 + tx*4];
      acc[0][0]+=a4.x*b4.x; acc[0][1]+=a4.x*b4.y; acc[0][2]+=a4.x*b4.z; acc[0][3]+=a4.x*b4.w;
      acc[1][0]+=a4.y*b4.x; acc[1][1]+=a4.y*b4.y; acc[1][2]+=a4.y*b4.z; acc[1][3]+=a4.y*b4.w;
      acc[2][0]+=a4.z*b4.x; acc[2][1]+=a4.z*b4.y; acc[2][2]+=a4.z*b4.z; acc[2][3]+=a4.z*b4.w;
      acc[3][0]+=a4.w*b4.x; acc[3][1]+=a4.w*b4.y; acc[3][2]+=a4.w*b4.z; acc[3][3]+=a4.w*b4.w;
    }
    __syncthreads();
    cur ^= 1;
  }

  #pragma unroll
  for (int i=0;i<4;i++){
    int co = co0 + ty*4 + i;
    float bco = bias ? bias[b*Cout + co] : 0.f;
    float* op = out0 + ((size_t)b*Cout + co)*N;
    float sv=0.f, qv=0.f;
    #pragma unroll
    for (int j=0;j<4;j++){
      int n = n0 + tx*4 + j;
      float v = acc[i][j] + bco;
      if (res) v += res[((size_t)b*Cout + co)*N + n];
      op[n] = v;
      sv += v; qv += v*v;
    }
    if (part){
      sv += __shfl_xor(sv,1); sv += __shfl_xor(sv,2); sv += __shfl_xor(sv,4); sv += __shfl_xor(sv,8);
      qv += __shfl_xor(qv,1); qv += __shfl_xor(qv,2); qv += __shfl_xor(qv,4); qv += __shfl_xor(qv,8);
      if (tx==0)
        part[(size_t)(b*Cout + co)*nparts + blockIdx.x] = make_float2(sv, qv);
    }
  }
  (void)mode;
}

// ---------------- small pointwise conv (NM-sized) ----------------
__global__ __launch_bounds__(256) void k_pw(const float* __restrict__ in, const float* __restrict__ WT,
                    const float2* __restrict__ tf, int relu,
                    int Cin, int Cout, int N,
                    const float* __restrict__ res,
                    float* __restrict__ out0,
                    __hip_bfloat16* __restrict__ qnm, __hip_bfloat16* __restrict__ vdm,
                    int mode){
  int b = blockIdx.z;
  int n0 = blockIdx.x*64, co0 = blockIdx.y*64;
  int tx = threadIdx.x & 15, ty = threadIdx.x >> 4;
  int cc = threadIdx.x & 63, g = threadIdx.x >> 6;
  __shared__ float wl[32][68];
  __shared__ float il[32][68];
  float acc[4][4] = {};
  const float* inb = in + (size_t)b*Cin*N;

  float rw[8], rv[8], ta[8], tb[8];
  #pragma unroll
  for (int rr=0;rr<8;rr++){ ta[rr]=1.f; tb[rr]=0.f; }
  #pragma unroll
  for (int rr=0;rr<8;rr++){
    int ci = g + 4*rr;
    rw[rr] = WT[(size_t)ci*Cout + co0 + cc];
    rv[rr] = inb[(size_t)ci*N + n0 + cc];
    if (tf){ float2 t = tf[b*Cin + ci]; ta[rr]=t.x; tb[rr]=t.y; }
  }

  for (int c0=0;c0<Cin;c0+=32){
    __syncthreads();
    #pragma unroll
    for (int rr=0;rr<8;rr++){
      int ci = g + 4*rr;
      wl[ci][cc] = rw[rr];
      float v = ta[rr]*rv[rr] + tb[rr];
      if (relu) v = fmaxf(v, 0.f);
      il[ci][cc] = v;
    }
    __syncthreads();
    if (c0+32 < Cin){
      int c0n = c0+32;
      #pragma unroll
      for (int rr=0;rr<8;rr++){
        int ci = g + 4*rr;
        rw[rr] = WT[(size_t)(c0n+ci)*Cout + co0 + cc];
        rv[rr] = inb[(size_t)(c0n+ci)*N + n0 + cc];
        if (tf){ float2 t = tf[b*Cin + c0n + ci]; ta[rr]=t.x; tb[rr]=t.y; }
      }
    }
    #pragma unroll
    for (int ci=0;ci<32;ci++){
      float4 a4 = *(const float4*)&wl[ci][ty*4];
      float4 b4 = *(const float4*)&il[ci][tx*4];
      acc[0][0]+=a4.x*b4.x; acc[0][1]+=a4.x*b4.y; acc[0][2]+=a4.x*b4.z; acc[0][3]+=a4.x*b4.w;
      acc[1][0]+=a4.y*b4.x; acc[1][1]+=a4.y*b4.y; acc[1][2]+=a4.y*b4.z; acc[1][3]+=a4.y*b4.w;
      acc[2][0]+=a4.z*b4.x; acc[2][1]+=a4.z*b4.y; acc[2][2]+=a4.z*b4.z; acc[2][3]+=a4.z*b4.w;
      acc[3][0]+=a4.w*b4.x; acc[3][1]+=a4.w*b4.y; acc[3][2]+=a4.w*b4.z; acc[3][3]+=a4.w*b4.w;
    }
  }
  if (mode==0){
    #pragma unroll
    for (int i=0;i<4;i++){
      int co = co0 + ty*4 + i;
      float* op = out0 + ((size_t)b*Cout + co)*N;
      #pragma unroll
      for (int j=0;j<4;j++){
        int n = n0 + tx*4 + j;
        float v = acc[i][j];
        if (res) v += res[((size_t)b*Cout + co)*N + n];
        op[n] = v;
      }
    }
  } else {
    int ccbase = (co0 & 255) + ty*4;
    int dd = ccbase >> 2;
    bool isq = (co0 < 256);
    #pragma unroll
    for (int i=0;i<4;i++){
      int bhid = b*4 + i;
      #pragma unroll
      for (int j=0;j<4;j++){
        int n = n0 + tx*4 + j;
        __hip_bfloat16 v = __float2bfloat16(acc[i][j]);
        if (isq) qnm[((size_t)bhid*N + n)*64 + dd] = v;
        else     vdm[((size_t)(bhid*64 + dd))*N + n] = v;
      }
    }
  }
}

// ---------------- merged attention: interleaved fattn (odd bid) / mattn (even bid) ----------------
__global__ __launch_bounds__(256) void k_attn(const __hip_bfloat16* __restrict__ qf,
    const __hip_bfloat16* __restrict__ qm, const __hip_bfloat16* __restrict__ vm,
    const __hip_bfloat16* __restrict__ vf,
    float* __restrict__ fo, float* __restrict__ num, float* __restrict__ cs){
  __shared__ __hip_bfloat16 pl[4][2][16][40];
  __shared__ float rsl[4][32];
  int bid = blockIdx.x;
  int sub = bid >> 1;
  int w = threadIdx.x>>6, l = threadIdx.x&63;
  int lr = l&15, lg = l>>4;

  if (bid & 1){
    // ---- feat-direction ----
    int bh = sub/108, b = bh>>2, h = bh&3;
    int i0 = (sub%108)*128 + w*32;
    bf16x8 aq[2][2];
    #pragma unroll
    for (int g=0; g<2; g++){
      const __hip_bfloat16* qb = qf + ((size_t)bh*NF + i0 + g*16 + lr)*64 + lg*8;
      aq[g][0] = *(const bf16x8*)(qb);
      aq[g][1] = *(const bf16x8*)(qb + 32);
    }
    f32x4 facc[2][4];
    #pragma unroll
    for (int g=0; g<2; g++)
      #pragma unroll
      for (int t=0;t<4;t++){ facc[g][t][0]=0.f; facc[g][t][1]=0.f; facc[g][t][2]=0.f; facc[g][t][3]=0.f; }
    float rs[2][4] = {};
    const __hip_bfloat16* kbase = qm + ((size_t)bh*NM + lr)*64 + lg*8;
    const __hip_bfloat16* vbase = vm + ((size_t)bh*64 + lr)*NM + lg*8;

    auto fcomp = [&](bf16x8 K0, bf16x8 K1, bf16x8 K2, bf16x8 K3,
                     bf16x8 V0, bf16x8 V1, bf16x8 V2, bf16x8 V3){
      __builtin_amdgcn_s_setprio(1);
      f32x4 s[2][2];
      #pragma unroll
      for (int g=0; g<2; g++){
        f32x4 s0 = {0.f,0.f,0.f,0.f}, s1 = {0.f,0.f,0.f,0.f};
        s0 = __builtin_amdgcn_mfma_f32_16x16x32_bf16(aq[g][0], K0, s0, 0,0,0);
        s0 = __builtin_amdgcn_mfma_f32_16x16x32_bf16(aq[g][1], K1, s0, 0,0,0);
        s1 = __builtin_amdgcn_mfma_f32_16x16x32_bf16(aq[g][0], K2, s1, 0,0,0);
        s1 = __builtin_amdgcn_mfma_f32_16x16x32_bf16(aq[g][1], K3, s1, 0,0,0);
        s[g][0] = s0; s[g][1] = s1;
      }
      __builtin_amdgcn_s_setprio(0);
      #pragma unroll
      for (int g=0; g<2; g++){
        #pragma unroll
        for (int r=0;r<4;r++){
          float p0 = fexp2(s[g][0][r]*0.18033688f);
          float p1 = fexp2(s[g][1][r]*0.18033688f);
          pl[w][g][4*lg+r][lr]    = __float2bfloat16(p0);
          pl[w][g][4*lg+r][16+lr] = __float2bfloat16(p1);
          rs[g][r] += p0 + p1;
        }
      }
      __builtin_amdgcn_s_setprio(1);
      #pragma unroll
      for (int g=0; g<2; g++){
        bf16x8 bp = *(const bf16x8*)&pl[w][g][lr][lg*8];
        facc[g][0] = __builtin_amdgcn_mfma_f32_16x16x32_bf16(V0, bp, facc[g][0], 0,0,0);
        facc[g][1] = __builtin_amdgcn_mfma_f32_16x16x32_bf16(V1, bp, facc[g][1], 0,0,0);
        facc[g][2] = __builtin_amdgcn_mfma_f32_16x16x32_bf16(V2, bp, facc[g][2], 0,0,0);
        facc[g][3] = __builtin_amdgcn_mfma_f32_16x16x32_bf16(V3, bp, facc[g][3], 0,0,0);
      }
      __builtin_amdgcn_s_setprio(0);
    };

    bf16x8 kA0,kA1,kA2,kA3,vA0,vA1,vA2,vA3;
    bf16x8 kB0,kB1,kB2,kB3,vB0,vB1,vB2,vB3;
    #define FLOAD(KP,VP,J0) \
      KP##0 = *(const bf16x8*)(kbase + (size_t)(J0)*64); \
      KP##1 = *(const bf16x8*)(kbase + (size_t)(J0)*64 + 32); \
      KP##2 = *(const bf16x8*)(kbase + (size_t)(J0)*64 + 1024); \
      KP##3 = *(const bf16x8*)(kbase + (size_t)(J0)*64 + 1056); \
      VP##0 = *(const bf16x8*)(vbase + (J0)); \
      VP##1 = *(const bf16x8*)(vbase + 16*NM + (J0)); \
      VP##2 = *(const bf16x8*)(vbase + 32*NM + (J0)); \
      VP##3 = *(const bf16x8*)(vbase + 48*NM + (J0));

    FLOAD(kA,vA,0)
    for (int jt=0; jt<16; jt+=2){
      FLOAD(kB,vB,(jt+1)*32)
      fcomp(kA0,kA1,kA2,kA3,vA0,vA1,vA2,vA3);
      if (jt+2 < 16){ FLOAD(kA,vA,(jt+2)*32) }
      fcomp(kB0,kB1,kB2,kB3,vB0,vB1,vB2,vB3);
    }
    #undef FLOAD

    #pragma unroll
    for (int g=0; g<2; g++)
      #pragma unroll
      for (int r=0;r<4;r++){
        float v = rs[g][r];
        v += __shfl_xor(v,1); v += __shfl_xor(v,2); v += __shfl_xor(v,4); v += __shfl_xor(v,8);
        if (lr==0) rsl[w][g*16 + 4*lg+r] = v;
      }
    __syncthreads();
    #pragma unroll
    for (int g=0; g<2; g++){
      float inv = 1.f / rsl[w][g*16 + lr];
      #pragma unroll
      for (int dt=0; dt<4; dt++){
        #pragma unroll
        for (int r=0;r<4;r++){
          int d = dt*16 + 4*lg + r;
          fo[((size_t)(b*256 + d*4 + h))*NF + i0 + g*16 + lr] = facc[g][dt][r]*inv;
        }
      }
    }
  } else {
    // ---- map-direction: 2 j-groups per wave, register-loaded F/V ----
    int ic = sub%27, jb = (sub/27)&3, bh = sub/108;
    int jt0 = jb*128 + w*16;
    int jt1 = jt0 + 64;
    bf16x8 am[2][2];
    {
      const __hip_bfloat16* ab0 = qm + ((size_t)bh*NM + jt0 + lr)*64 + lg*8;
      const __hip_bfloat16* ab1 = qm + ((size_t)bh*NM + jt1 + lr)*64 + lg*8;
      am[0][0] = *(const bf16x8*)(ab0);
      am[0][1] = *(const bf16x8*)(ab0 + 32);
      am[1][0] = *(const bf16x8*)(ab1);
      am[1][1] = *(const bf16x8*)(ab1 + 32);
    }
    f32x4 macc[2][4];
    #pragma unroll
    for (int jg=0;jg<2;jg++)
      #pragma unroll
      for (int t=0;t<4;t++){ macc[jg][t][0]=0.f; macc[jg][t][1]=0.f; macc[jg][t][2]=0.f; macc[jg][t][3]=0.f; }
    float csr[2][4] = {};
    const __hip_bfloat16* fbase  = qf + ((size_t)bh*NF + lr)*64 + lg*8;
    const __hip_bfloat16* vfbase = vf + ((size_t)bh*64 + lr)*NF + lg*8;

    auto mcomp = [&](bf16x8 F0, bf16x8 F1, bf16x8 F2, bf16x8 F3,
                     bf16x8 V0, bf16x8 V1, bf16x8 V2, bf16x8 V3){
      __builtin_amdgcn_s_setprio(1);
      f32x4 s[2][2];
      #pragma unroll
      for (int jg=0;jg<2;jg++){
        f32x4 s0 = {0.f,0.f,0.f,0.f}, s1 = {0.f,0.f,0.f,0.f};
        s0 = __builtin_amdgcn_mfma_f32_16x16x32_bf16(am[jg][0], F0, s0, 0,0,0);
        s0 = __builtin_amdgcn_mfma_f32_16x16x32_bf16(am[jg][1], F1, s0, 0,0,0);
        s1 = __builtin_amdgcn_mfma_f32_16x16x32_bf16(am[jg][0], F2, s1, 0,0,0);
        s1 = __builtin_amdgcn_mfma_f32_16x16x32_bf16(am[jg][1], F3, s1, 0,0,0);
        s[jg][0] = s0; s[jg][1] = s1;
      }
      __builtin_amdgcn_s_setprio(0);
      #pragma unroll
      for (int jg=0;jg<2;jg++){
        #pragma unroll
        for (int r=0;r<4;r++){
          float p0 = fexp2(s[jg][0][r]*0.18033688f);
          float p1 = fexp2(s[jg][1][r]*0.18033688f);
          pl[w][jg][4*lg+r][lr]    = __float2bfloat16(p0);
          pl[w][jg][4*lg+r][16+lr] = __float2bfloat16(p1);
          csr[jg][r] += p0 + p1;
        }
      }
      __builtin_amdgcn_s_setprio(1);
      #pragma unroll
      for (int jg=0;jg<2;jg++){
        bf16x8 bp = *(const bf16x8*)&pl[w][jg][lr][lg*8];
        macc[jg][0] = __builtin_amdgcn_mfma_f32_16x16x32_bf16(V0, bp, macc[jg][0], 0,0,0);
        macc[jg][1] = __builtin_amdgcn_mfma_f32_16x16x32_bf16(V1, bp, macc[jg][1], 0,0,0);
        macc[jg][2] = __builtin_amdgcn_mfma_f32_16x16x32_bf16(V2, bp, macc[jg][2], 0,0,0);
        macc[jg][3] = __builtin_amdgcn_mfma_f32_16x16x32_bf16(V3, bp, macc[jg][3], 0,0,0);
      }
      __builtin_amdgcn_s_setprio(0);
    };

    bf16x8 fA0,fA1,fA2,fA3,vA0,vA1,vA2,vA3;
    bf16x8 fB0,fB1,fB2,fB3,vB0,vB1,vB2,vB3;
    #define MLOAD(FP,VP,I0) \
      FP##0 = *(const bf16x8*)(fbase + (size_t)(I0)*64); \
      FP##1 = *(const bf16x8*)(fbase + (size_t)(I0)*64 + 32); \
      FP##2 = *(const bf16x8*)(fbase + (size_t)(I0)*64 + 1024); \
      FP##3 = *(const bf16x8*)(fbase + (size_t)(I0)*64 + 1056); \
      VP##0 = *(const bf16x8*)(vfbase + (size_t)(I0)); \
      VP##1 = *(const bf16x8*)(vfbase + (size_t)16*NF + (I0)); \
      VP##2 = *(const bf16x8*)(vfbase + (size_t)32*NF + (I0)); \
      VP##3 = *(const bf16x8*)(vfbase + (size_t)48*NF + (I0));

    int ibase = ic*512;
    MLOAD(fA,vA, ibase)
    for (int is=0; is<16; is+=2){
      MLOAD(fB,vB, ibase + (is+1)*32)
      mcomp(fA0,fA1,fA2,fA3,vA0,vA1,vA2,vA3);
      if (is+2<16){ MLOAD(fA,vA, ibase + (is+2)*32) }
      mcomp(fB0,fB1,fB2,fB3,vB0,vB1,vB2,vB3);
    }
    #undef MLOAD

    size_t nb = ((size_t)(ic*8 + bh)*64)*512;
    #pragma unroll
    for (int jg=0;jg<2;jg++){
      int jt = jg ? jt1 : jt0;
      #pragma unroll
      for (int dt=0;dt<4;dt++){
        #pragma unroll
        for (int r=0;r<4;r++){
          num[nb + (size_t)(dt*16 + 4*lg + r)*512 + jt + lr] = macc[jg][dt][r];
        }
      }
    }
    #pragma unroll
    for (int jg=0;jg<2;jg++){
      int jt = jg ? jt1 : jt0;
      #pragma unroll
      for (int r=0;r<4;r++){
        float v = csr[jg][r];
        v += __shfl_xor(v,1); v += __shfl_xor(v,2); v += __shfl_xor(v,4); v += __shfl_xor(v,8);
        if (lr==0) cs[(size_t)(ic*8 + bh)*512 + jt + 4*lg + r] = v;
      }
    }
  }
}

// ---------------- combine map-dir partials -> ma merged-channel layout (coalesced) ----------------
__global__ void k_comb(const float* __restrict__ num, const float* __restrict__ cs,
                       float* __restrict__ ma){
  int idx = blockIdx.x*256 + threadIdx.x;
  if (idx >= 8*512*64) return;
  int bh = idx>>15; int rem = idx&32767; int d = rem>>9; int j = rem&511;
  float s=0.f, c=0.f;
  for (int ic=0;ic<NIC;ic++){
    s += num[((size_t)(ic*8+bh)*64 + d)*512 + j];
    c += cs[(size_t)(ic*8+bh)*512 + j];
  }
  int b = bh>>2, h = bh&3;
  ma[((size_t)(b*256 + d*4 + h))*NM + j] = s/c;
}

// ---------------- squeeze-excite MLP (tiny) ----------------
__global__ void k_se(const float2* __restrict__ st, const float* __restrict__ w1, const float* __restrict__ b1,
                     const float* __restrict__ w2, const float* __restrict__ b2, float* __restrict__ sout){
  int b = blockIdx.x; int t = threadIdx.x;
  __shared__ float mean[512]; __shared__ float s1[128];
  mean[t]     = st[b*512 + t].x;
  mean[t+256] = st[b*512 + t + 256].x;
  __syncthreads();
  if (t<128){
    float a = b1[t];
    for (int c=0;c<512;c++) a += w1[t*512+c]*mean[c];
    s1[t] = fmaxf(a, 0.f);
  }
  __syncthreads();
  for (int o=t;o<512;o+=256){
    float a = b2[o];
    for (int c=0;c<128;c++) a += w2[o*128+c]*s1[c];
    sout[b*512+o] = 1.f/(1.f+__expf(-a));
  }
}

extern "C" void kernel_launch(void* const* d_in, const int* in_sizes, int n_in,
                              void* d_out, int out_size, void* d_ws, size_t ws_size,
                              hipStream_t stream){
  const float* x     = (const float*)d_in[0];
  const float* smap  = (const float*)d_in[1];
  const float* wfdw  = (const float*)d_in[2];
  const float* wfpw  = (const float*)d_in[3];
  const float* wmqv  = (const float*)d_in[4];
  const float* wodw  = (const float*)d_in[5];
  const float* wopw  = (const float*)d_in[6];
  const float* wmout = (const float*)d_in[7];
  const float* wexp  = (const float*)d_in[8];
  const float* wdw   = (const float*)d_in[9];
  const float* wse1  = (const float*)d_in[10];
  const float* bse1  = (const float*)d_in[11];
  const float* wse2  = (const float*)d_in[12];
  const float* bse2  = (const float*)d_in[13];
  const float* wpw   = (const float*)d_in[14];

  float* out  = (float*)d_out;                        // [2][128][NF]
  float* mout = out + (size_t)2*128*NF;               // [2][128][NM]

  float* W = (float*)d_ws;
  size_t o = 0;
  __hip_bfloat16* qf = (__hip_bfloat16*)(W + o); o += (size_t)8*NF*32;   // bf16 [8][NF][64]
  __hip_bfloat16* vf = (__hip_bfloat16*)(W + o); o += (size_t)8*NF*32;   // bf16 [8][64][NF]
  float* fdw  = W + o; o += (size_t)2*128*NF;          // reused as 'act' for MBConv expand
  float* num  = W + o; o += (size_t)NIC*8*64*512;
  __hip_bfloat16* qm = (__hip_bfloat16*)(W + o); o += 8*NM*32;           // bf16 [8][512][64]
  __hip_bfloat16* vm = (__hip_bfloat16*)(W + o); o += 8*NM*32;           // bf16 [8][64][512]
  float* csb  = W + o; o += (size_t)NIC*8*512;
  float* ma   = W + o; o += (size_t)2*256*NM;
  float* h2   = (float*)d_ws;
  float* fo   = W + o; o += (size_t)2*256*NF;
  float* fdw2 = W + o; o += (size_t)2*256*NF;
  float* h1 = fo;
  float* wTf  = W + o; o += 512*128;
  float* wTm  = W + o; o += 512*128;
  float* wTo  = W + o; o += 128*256;
  float* wTmo = W + o; o += 128*256;
  float* wTe  = W + o; o += 512*128;
  float* wTp  = W + o; o += 128*512;
  float* wfP  = W + o; o += (size_t)2*512*128;         // folded final weights
  float* biasP= W + o; o += 2*128;                     // folded final bias
  float2* partO = (float2*)(W+o); o += (size_t)2*256*216;
  float2* partH1= (float2*)(W+o); o += (size_t)2*1024*216;
  float2* tfO = (float2*)(W+o); o += 512;
  float2* tfH1= (float2*)(W+o); o += 2048;
  float2* stA = (float2*)(W+o); o += 512;
  float2* tfA = (float2*)(W+o); o += 512;
  float2* stM = (float2*)(W+o); o += 512;
  float2* tfM = (float2*)(W+o); o += 512;
  float2* stH2= (float2*)(W+o); o += 2048;
  float2* tfH = (float2*)(W+o); o += 2048;
  float* sbuf = W + o; o += 1024;
  (void)ws_size; (void)in_sizes; (void)n_in; (void)out_size;

  // merged weight transposes
  k_transpose6<<<dim3(256,6),256,0,stream>>>(wfpw,wTf, wmqv,wTm, wopw,wTo, wmout,wTmo, wexp,wTe, wpw,wTp);

  // feat path
  k_stats<<<256,256,0,stream>>>(x, stA, NF, tfA);
  k_dw3t<<<256,256,0,stream>>>(x, wfdw, tfA, fdw, 128, 0, nullptr);
  k_pw2<<<dim3(216,4,2),256,0,stream>>>(fdw, wTf, nullptr, 128,512,NF,0, nullptr, nullptr, qf, vf, 1, nullptr,0);

  // map path
  k_stats<<<256,256,0,stream>>>(smap, stM, NM, tfM);
  k_pw<<<dim3(8,8,2),256,0,stream>>>(smap, wTm, tfM,0, 128,512,NM, nullptr, nullptr, qm, vm, 1);

  // attention, both directions merged + interleaved (MFMA)
  k_attn<<<dim3(1728),256,0,stream>>>(qf, qm, vm, vf, fo, num, csb);
  k_comb<<<1024,256,0,stream>>>(num, csb, ma);

  // output convs + residuals (out stats via per-block partials -> partO)
  k_dw3t<<<512,256,0,stream>>>(fo, wodw, nullptr, fdw2, 256, 0, nullptr);
  k_pw2s<<<dim3(216,2,2),256,0,stream>>>(fdw2, wTo, nullptr, 256,128,NF,0, x, out, 0, partO,216);
  k_pw<<<dim3(8,2,2),256,0,stream>>>(ma, wTmo, nullptr,0, 256,128,NM, smap, mout, nullptr,nullptr, 0);

  // MBConv
  k_red<<<64,256,0,stream>>>(partO, 216, 256, 1.f/NF, tfO);
  k_act<<<3456,256,0,stream>>>(out, tfO, fdw);          // act = relu(inorm(out)), reuses fdw
  k_pw2<<<dim3(216,4,2),256,0,stream>>>(fdw, wTe, nullptr, 128,512,NF,0, nullptr, h1, nullptr,nullptr, 0, partH1,216);

  k_red<<<256,256,0,stream>>>(partH1, 216, 1024, 1.f/NF, tfH1);
  k_dw3t<<<1024,256,0,stream>>>(h1, wdw, tfH1, h2, 512, 1, stH2);

  k_se<<<2,256,0,stream>>>(stH2, wse1,bse1,wse2,bse2, sbuf);
  k_make_tf<<<4,256,0,stream>>>(stH2, sbuf, tfH, 1024);
  k_fold<<<dim3(128,2),256,0,stream>>>(wTp, tfH, wfP, biasP);
  k_pw2s<<<dim3(216,2,2),256,0,stream>>>(h2, wfP, biasP, 512,128,NF,512*128, out, out, 0, nullptr,0);
}